// Round 11
// baseline (578.010 us; speedup 1.0000x reference)
//
#include <hip/hip_runtime.h>
#include <hip/hip_bf16.h>
#include <stdint.h>

// JointAttention: B=1, L=512(txt), N=4096(img), HID=1536, H=12, D=128
// Round 13: attn pipeline deepened. R10's 32x32 swapped-operand core kept
// verbatim; main loop restructured: LDS double-buffer (64KB exactly: K0,V0,
// K1,V1 16KB each), TWO register staging sets (A/B) at 2-tile prefetch
// distance, parity-unrolled loop (static reg indexing), ONE barrier per tile.
// vmcnt at writeKV drains loads issued 2 tiles earlier -> fully covered by
// compute (R10: ~42% no-issue stall, cover was only 1 tile). Epilogue sO/sML
// alias into the buffers after the loop. GEMMs unchanged.
// ws (u16 elems): qb[0) kb[7077888) vb[14155776) ob[21233664)
//   txtb[28311552) imgb[29097984) Wqtb[35389440) Wqib[42467328)
//   Wotb[49545216) Woib[51904512) end 54263808 -> 108.5 MB.

typedef __attribute__((ext_vector_type(8))) short short8;
typedef __attribute__((ext_vector_type(4))) float floatx4;
typedef __attribute__((ext_vector_type(16))) float floatx16;

#define DEV __device__ __forceinline__

DEV float bf2f(uint16_t s) {
  union { uint32_t u; float f; } v;
  v.u = (uint32_t)s << 16;
  return v.f;
}
DEV uint16_t f2bf(float f) {
  __hip_bfloat16 h = __float2bfloat16(f);
  return __builtin_bit_cast(uint16_t, h);
}
DEV uint32_t pk2(float a, float b) {
  return (uint32_t)f2bf(a) | ((uint32_t)f2bf(b) << 16);
}

// Distinguish bf16 vs fp32 buffers (majority vote on exponent sanity).
DEV bool detect_bf16(const void* p) {
  const uint16_t* u = (const uint16_t*)p;
  int sane = 0;
  for (int i = 0; i < 64; ++i) {
    int e = (u[2 * i] >> 7) & 0xFF;
    sane += (e > 90 && e < 145) ? 1 : 0;
  }
  return sane >= 40;
}

DEV short8 load8(const void* base, long idx, bool bf) {
  if (bf) return *(const short8*)((const uint16_t*)base + idx);
  const floatx4* f = (const floatx4*)((const float*)base + idx);
  floatx4 a = f[0], b = f[1];
  short8 r;
  r[0] = (short)f2bf(a[0]); r[1] = (short)f2bf(a[1]);
  r[2] = (short)f2bf(a[2]); r[3] = (short)f2bf(a[3]);
  r[4] = (short)f2bf(b[0]); r[5] = (short)f2bf(b[1]);
  r[6] = (short)f2bf(b[2]); r[7] = (short)f2bf(b[3]);
  return r;
}

DEV float loadElem(const void* base, long idx, bool bf) {
  return bf ? bf2f(((const uint16_t*)base)[idx]) : ((const float*)base)[idx];
}

// ---------------------------------------------------------------------------
// One-time fp32->bf16 (or bf16 copy) of the 6 GEMM operand tensors into ws.
__global__ void convert6(const void* s0, const void* s1, const void* s2,
                         const void* s3, const void* s4, const void* s5,
                         uint16_t* ws) {
  const void* s;
  uint16_t* d;
  long n;
  switch (blockIdx.y) {
    case 0: s = s0; d = ws + 28311552L; n = 786432L; break;   // txt
    case 1: s = s1; d = ws + 29097984L; n = 6291456L; break;  // img
    case 2: s = s2; d = ws + 35389440L; n = 7077888L; break;  // W_txt_qkv
    case 3: s = s3; d = ws + 42467328L; n = 7077888L; break;  // W_img_qkv
    case 4: s = s4; d = ws + 49545216L; n = 2359296L; break;  // W_txt_out
    default: s = s5; d = ws + 51904512L; n = 2359296L; break; // W_img_out
  }
  const bool bf = detect_bf16(s);
  const long stride = (long)gridDim.x * blockDim.x * 8;
  for (long i = ((long)blockIdx.x * blockDim.x + threadIdx.x) * 8; i < n;
       i += stride) {
    if (bf) {
      *(short8*)(d + i) = *(const short8*)((const uint16_t*)s + i);
    } else {
      const floatx4* f = (const floatx4*)((const float*)s + i);
      floatx4 a = f[0], b = f[1];
      short8 r;
      r[0] = (short)f2bf(a[0]); r[1] = (short)f2bf(a[1]);
      r[2] = (short)f2bf(a[2]); r[3] = (short)f2bf(a[3]);
      r[4] = (short)f2bf(b[0]); r[5] = (short)f2bf(b[1]);
      r[6] = (short)f2bf(b[2]); r[7] = (short)f2bf(b[3]);
      *(short8*)(d + i) = r;
    }
  }
}

// ---------------------------------------------------------------------------
// acc[4][4] for C tile (bm,bn) of A[M,K] * B[N,K]^T via bf16 MFMA.
// 128x128 tile, BK=32, register staging + ds_write_b128, XOR chunk swizzle.
DEV void gemm_core(const void* A, const void* B, bool abf, bool bbf, long bm,
                   long bn, int K, uint16_t* sA, uint16_t* sB,
                   floatx4 (&acc)[4][4]) {
  const int t = threadIdx.x;
  const int lane = t & 63, wave = t >> 6, l16 = lane & 15, quad = lane >> 4;
  const int srow = t >> 2, c = t & 3, g = c ^ (srow & 3);
  const int wm = (wave >> 1) * 64, wn = (wave & 1) * 64;
  const int fsl = (quad ^ (l16 & 3)) * 8;
  for (int k0 = 0; k0 < K; k0 += 32) {
    short8 a0 = load8(A, (bm + srow) * (long)K + k0 + g * 8, abf);
    short8 a1 = load8(A, (bm + 64 + srow) * (long)K + k0 + g * 8, abf);
    short8 b0 = load8(B, (bn + srow) * (long)K + k0 + g * 8, bbf);
    short8 b1 = load8(B, (bn + 64 + srow) * (long)K + k0 + g * 8, bbf);
    __syncthreads();  // prev-iter frag reads done before overwrite
    *(short8*)(sA + srow * 32 + c * 8) = a0;
    *(short8*)(sA + (64 + srow) * 32 + c * 8) = a1;
    *(short8*)(sB + srow * 32 + c * 8) = b0;
    *(short8*)(sB + (64 + srow) * 32 + c * 8) = b1;
    __syncthreads();
    short8 af[4], bfr[4];
#pragma unroll
    for (int i = 0; i < 4; ++i) {
      af[i] = *(const short8*)(sA + (wm + i * 16 + l16) * 32 + fsl);
      bfr[i] = *(const short8*)(sB + (wn + i * 16 + l16) * 32 + fsl);
    }
#pragma unroll
    for (int i = 0; i < 4; ++i)
#pragma unroll
      for (int j = 0; j < 4; ++j)
        acc[i][j] = __builtin_amdgcn_mfma_f32_16x16x32_bf16(af[i], bfr[j],
                                                            acc[i][j], 0, 0, 0);
  }
}

// ---------------------------------------------------------------------------
// Merged QKV gemm with fused scatter + rope + q-prescale (SCALE*log2e).
// Column tile = one (tensor tt, head h). q/k/v row-major [H][4608][128].
__global__ __launch_bounds__(256, 2) void qkv_gemm(
    const void* Atxt, const void* Aimg, const void* Btxt, const void* Bimg,
    const void* rope, const void* det, int conv, uint16_t* qb, uint16_t* kb,
    uint16_t* vb) {
  __shared__ uint16_t sA[128 * 32], sB[128 * 32];
  const bool dbf = detect_bf16(det);      // original input dtype (rope)
  const bool bf = conv ? true : dbf;      // A/B operand dtype
  const int bmb = blockIdx.y;
  const long g0 = (long)bmb * 128;        // global seq row of this block
  const bool is_img = bmb >= 4;           // 4*128 == 512 txt rows
  const void* A = is_img ? Aimg : Atxt;
  const void* B = is_img ? Bimg : Btxt;
  const long bmA = is_img ? g0 - 512 : g0;
  const long bn = (long)blockIdx.x * 128;
  floatx4 acc[4][4] = {};
  gemm_core(A, B, bf, bf, bmA, bn, 1536, sA, sB, acc);

  const int t = threadIdx.x, lane = t & 63, wave = t >> 6;
  const int l16 = lane & 15, quad = lane >> 4;
  const int wm = (wave >> 1) * 64, wn = (wave & 1) * 64;
  const int th = blockIdx.x;
  const int tt = th / 12, h = th - tt * 12;
  uint16_t* dst = tt == 0 ? qb : (tt == 1 ? kb : vb);
  const bool do_rope = is_img && (tt < 2);
#pragma unroll
  for (int i = 0; i < 4; ++i)
#pragma unroll
    for (int j = 0; j < 4; ++j)
#pragma unroll
      for (int r = 0; r < 4; ++r) {
        long g = g0 + wm + i * 16 + quad * 4 + r;  // global seq row
        int d = wn + j * 16 + l16;
        float v = acc[i][j][r];
        float p = __shfl_xor(v, 1);  // partner element of the rope pair
        if (do_rope) {
          int dp = d & ~1;
          long ri = (g - 512) * 128 + dp;
          float cc = loadElem(rope, ri, dbf);
          float ss = loadElem(rope, ri + 1, dbf);
          v = (d & 1) ? (v * cc + p * ss) : (v * cc - p * ss);
        }
        if (tt == 0) v *= 0.12751745f;  // D^-0.5 * log2(e)
        dst[((long)h * 4608 + g) * 128 + d] = f2bf(v);
      }
}

// ---------------------------------------------------------------------------
// Merged out-projection gemm.
__global__ __launch_bounds__(256, 2) void out_gemm(
    const uint16_t* Abf, const void* Btxt, const void* Bimg, const void* det,
    int conv, void* out) {
  __shared__ uint16_t sA[128 * 32], sB[128 * 32];
  const bool dbf = detect_bf16(det);
  const bool bbf = conv ? true : dbf;
  const int bmb = blockIdx.y;
  const long bm = (long)bmb * 128;
  const void* B = bmb >= 4 ? Bimg : Btxt;
  const long bn = (long)blockIdx.x * 128;
  floatx4 acc[4][4] = {};
  gemm_core(Abf, B, true, bbf, bm, bn, 1536, sA, sB, acc);

  const int t = threadIdx.x, lane = t & 63, wave = t >> 6;
  const int l16 = lane & 15, quad = lane >> 4;
  const int wm = (wave >> 1) * 64, wn = (wave & 1) * 64;
#pragma unroll
  for (int i = 0; i < 4; ++i)
#pragma unroll
    for (int j = 0; j < 4; ++j)
#pragma unroll
      for (int r = 0; r < 4; ++r) {
        long row = bm + wm + i * 16 + quad * 4 + r;
        long col = bn + wn + j * 16 + l16;
        long idx = row * 1536 + col;
        if (dbf) ((uint16_t*)out)[idx] = f2bf(acc[i][j][r]);
        else ((float*)out)[idx] = acc[i][j][r];
      }
}

// ---------------------------------------------------------------------------
// Flash attention, 32x32x16 MFMA swapped operands, KVBLK=64, LDS dbuf (64KB),
// 2-tile-deep register prefetch (sets A/B), parity-unrolled, 1 barrier/tile.
// Wave layout / fragment algebra identical to R10 (verified passing):
//   lane l: q = q0 + (l&31), hi = l>>5; wq = wave>>1, wk = wave&1.
//   QK: sc = mfma(K,Q) -> S^T[key][q]; PV: accO = mfma(V^T,P^T) -> O^T[d][q].
// Buf0 holds even tiles, buf1 odd tiles (fixed roles).
__global__ __launch_bounds__(256, 2) void attn(
    const uint16_t* __restrict__ qb, const uint16_t* __restrict__ kb,
    const uint16_t* __restrict__ vb, uint16_t* __restrict__ ob) {
  __shared__ __align__(16) char smem[65536];
  uint16_t* sK0 = (uint16_t*)smem;               // even-tile K  [64][128]
  uint16_t* sV0 = (uint16_t*)(smem + 16384);     // even-tile Vt [128][64]
  uint16_t* sK1 = (uint16_t*)(smem + 32768);     // odd-tile K
  uint16_t* sV1 = (uint16_t*)(smem + 49152);     // odd-tile Vt
  float* sO = (float*)smem;                      // epilogue reuse (33280B)
  float* sML = (float*)(smem + 33280);           // epilogue [4][32][2]

  const int t = threadIdx.x;
  const int lane = t & 63, wave = t >> 6;
  const int l31 = lane & 31, hi = lane >> 5;
  const int wq = wave >> 1, wk = wave & 1;
  const int kb0 = wk * 32;
  // XCD swizzle: bijective since 864 % 8 == 0
  const int bid = blockIdx.y * 72 + blockIdx.x;
  const int sw = (bid & 7) * 108 + (bid >> 3);
  const int h = sw / 72;
  const int q0 = (sw - h * 72) * 64 + wq * 32;

  const uint16_t* Qh = qb + (long)h * 4608 * 128;
  const uint16_t* Kh = kb + (long)h * 4608 * 128;
  const uint16_t* Vh = vb + (long)h * 4608 * 128;

  // Q as B-fragments: aq[dk] = Q[q0+l31][dk*16 + hi*8 .. +8]
  short8 aq[8];
#pragma unroll
  for (int dk = 0; dk < 8; ++dk)
    aq[dk] = *(const short8*)(Qh + (long)(q0 + l31) * 128 + dk * 16 + hi * 8);

  float m_i = -1e30f;
  float accL = 0.f;
  floatx16 accO[4] = {};  // accO[g][r]: d = g*32 + (r&3)+8*(r>>2)+4*hi

  // staging geometry (identical to R10)
  const int krow = t >> 2;        // 0..63
  const int kcb = (t & 3) * 4;    // K chunk base (4 chunks of 8 elems)
  const int vk = (t & 31) * 2;    // V key pair
  const int vdb = (t >> 5) * 16;  // V d base (16 d's per thread)

  short8 kregA[4], vregA[4], kregB[4], vregB[4];

  auto loadA = [&](int key0) {
    const uint16_t* kp = Kh + (long)(key0 + krow) * 128 + kcb * 8;
    kregA[0] = *(const short8*)(kp);
    kregA[1] = *(const short8*)(kp + 8);
    kregA[2] = *(const short8*)(kp + 16);
    kregA[3] = *(const short8*)(kp + 24);
    const uint16_t* vp = Vh + (long)(key0 + vk) * 128 + vdb;
    vregA[0] = *(const short8*)(vp);
    vregA[1] = *(const short8*)(vp + 8);
    vregA[2] = *(const short8*)(vp + 128);
    vregA[3] = *(const short8*)(vp + 136);
  };
  auto loadB = [&](int key0) {
    const uint16_t* kp = Kh + (long)(key0 + krow) * 128 + kcb * 8;
    kregB[0] = *(const short8*)(kp);
    kregB[1] = *(const short8*)(kp + 8);
    kregB[2] = *(const short8*)(kp + 16);
    kregB[3] = *(const short8*)(kp + 24);
    const uint16_t* vp = Vh + (long)(key0 + vk) * 128 + vdb;
    vregB[0] = *(const short8*)(vp);
    vregB[1] = *(const short8*)(vp + 8);
    vregB[2] = *(const short8*)(vp + 128);
    vregB[3] = *(const short8*)(vp + 136);
  };
  auto writeA = [&](uint16_t* sK, uint16_t* sV) {
#pragma unroll
    for (int j = 0; j < 4; ++j)
      *(short8*)(sK + krow * 128 + (((kcb + j) ^ (krow & 15)) * 8)) = kregA[j];
    char* vd = (char*)sV;
#pragma unroll
    for (int hf = 0; hf < 2; ++hf)
#pragma unroll
      for (int j = 0; j < 8; ++j) {
        const int d = vdb + hf * 8 + j;
        uint32_t pk = (uint16_t)vregA[hf][j] |
                      ((uint32_t)(uint16_t)vregA[2 + hf][j] << 16);
        *(uint32_t*)(vd + d * 128 + (((vk >> 3) ^ (d & 7)) * 16) +
                     (vk & 7) * 2) = pk;
      }
  };
  auto writeB = [&](uint16_t* sK, uint16_t* sV) {
#pragma unroll
    for (int j = 0; j < 4; ++j)
      *(short8*)(sK + krow * 128 + (((kcb + j) ^ (krow & 15)) * 8)) = kregB[j];
    char* vd = (char*)sV;
#pragma unroll
    for (int hf = 0; hf < 2; ++hf)
#pragma unroll
      for (int j = 0; j < 8; ++j) {
        const int d = vdb + hf * 8 + j;
        uint32_t pk = (uint16_t)vregB[hf][j] |
                      ((uint32_t)(uint16_t)vregB[2 + hf][j] << 16);
        *(uint32_t*)(vd + d * 128 + (((vk >> 3) ^ (d & 7)) * 16) +
                     (vk & 7) * 2) = pk;
      }
  };

  // compute one 64-key tile from (sKc, sVc); updates m_i, accL, accO.
  auto computeTile = [&](const uint16_t* sKc, const uint16_t* sVc) {
    floatx16 sc = {};
    __builtin_amdgcn_s_setprio(1);
#pragma unroll
    for (int dk = 0; dk < 8; ++dk) {
      short8 ak = *(const short8*)(
          sKc + (kb0 + l31) * 128 + (((dk * 2 + hi) ^ (l31 & 15)) * 8));
      sc = __builtin_amdgcn_mfma_f32_32x32x16_bf16(ak, aq[dk], sc, 0, 0, 0);
    }
    __builtin_amdgcn_s_setprio(0);

    float mx = sc[0];
#pragma unroll
    for (int r = 1; r < 16; ++r) mx = fmaxf(mx, sc[r]);
    mx = fmaxf(mx, __shfl_xor(mx, 32));
    if (!__all(mx - m_i <= 11.5f)) {
      float mn = fmaxf(m_i, mx);
      float al = exp2f(m_i - mn);
      m_i = mn;
      accL *= al;
#pragma unroll
      for (int g = 0; g < 4; ++g)
#pragma unroll
        for (int r = 0; r < 16; ++r) accO[g][r] *= al;
    }
#pragma unroll
    for (int r = 0; r < 16; ++r) sc[r] = exp2f(sc[r] - m_i);
    float s = 0.f;
#pragma unroll
    for (int r = 0; r < 16; ++r) s += sc[r];
    accL += s + __shfl_xor(s, 32);

    short8 pb[2];
#pragma unroll
    for (int sp = 0; sp < 2; ++sp) {
      uint32_t cA = pk2(sc[sp * 8 + 0], sc[sp * 8 + 1]);
      uint32_t cB = pk2(sc[sp * 8 + 2], sc[sp * 8 + 3]);
      uint32_t cC = pk2(sc[sp * 8 + 4], sc[sp * 8 + 5]);
      uint32_t cD = pk2(sc[sp * 8 + 6], sc[sp * 8 + 7]);
      uint32_t xA = (uint32_t)__shfl_xor((int)cA, 32);
      uint32_t xB = (uint32_t)__shfl_xor((int)cB, 32);
      uint32_t xC = (uint32_t)__shfl_xor((int)cC, 32);
      uint32_t xD = (uint32_t)__shfl_xor((int)cD, 32);
      union { short8 v; uint32_t u[4]; } w;
      w.u[0] = hi ? xC : cA;
      w.u[1] = hi ? xD : cB;
      w.u[2] = hi ? cC : xA;
      w.u[3] = hi ? cD : xB;
      pb[sp] = w.v;
    }

    __builtin_amdgcn_s_setprio(1);
#pragma unroll
    for (int g = 0; g < 4; ++g) {
      const int d = g * 32 + l31;
#pragma unroll
      for (int sp = 0; sp < 2; ++sp) {
        short8 av = *(const short8*)(
            (const char*)sVc + d * 128 +
            (((wk * 4 + sp * 2 + hi) ^ (d & 7)) * 16));
        accO[g] =
            __builtin_amdgcn_mfma_f32_32x32x16_bf16(av, pb[sp], accO[g], 0, 0, 0);
      }
    }
    __builtin_amdgcn_s_setprio(0);
  };

  // prologue: tile0 -> buf0 (via A), then A=tile1, B=tile2 in flight
  loadA(0);
  writeA(sK0, sV0);
  loadA(64);
  loadB(128);
  __syncthreads();

  // parity-unrolled main loop: buf0 = even tiles, buf1 = odd tiles.
  for (int kt = 0; kt < 72; kt += 2) {
    writeA(sK1, sV1);                   // stage tile kt+1 (A: 2 tiles old)
    if (kt + 3 < 72) loadA((kt + 3) * 64);
    computeTile(sK0, sV0);              // tile kt
    __syncthreads();
    if (kt + 2 < 72) writeB(sK0, sV0);  // stage tile kt+2
    if (kt + 4 < 72) loadB((kt + 4) * 64);
    computeTile(sK1, sV1);              // tile kt+1
    __syncthreads();
  }

  // ---- epilogue: merge the two key-half partials (exact) ----
  sML[(wave * 32 + l31) * 2 + 0] = m_i;
  sML[(wave * 32 + l31) * 2 + 1] = accL;
  __syncthreads();
  const float m0 = sML[((wq * 2 + 0) * 32 + l31) * 2 + 0];
  const float l0 = sML[((wq * 2 + 0) * 32 + l31) * 2 + 1];
  const float m1 = sML[((wq * 2 + 1) * 32 + l31) * 2 + 0];
  const float l1 = sML[((wq * 2 + 1) * 32 + l31) * 2 + 1];
  const float M = fmaxf(m0, m1);
  const float L = l0 * exp2f(m0 - M) + l1 * exp2f(m1 - M);
  const float fac = exp2f(m_i - M);
  float* myO = sO + wq * 4160 + l31 * 130;  // stride 130 (bank-friendly)
  __syncthreads();  // sML reads done before sO overwrites smem region
  if (wk == 1) {
#pragma unroll
    for (int g = 0; g < 4; ++g)
#pragma unroll
      for (int r = 0; r < 16; ++r) {
        const int d = g * 32 + (r & 3) + 8 * (r >> 2) + 4 * hi;
        myO[d] = accO[g][r] * fac;
      }
  }
  __syncthreads();
  if (wk == 0) {
    const float inv = 1.f / L;
    const long q = q0 + l31;
#pragma unroll
    for (int g = 0; g < 4; ++g)
#pragma unroll
      for (int rb = 0; rb < 4; ++rb) {
        const int d0 = g * 32 + 8 * rb + 4 * hi;
        uint64_t pk = 0;
#pragma unroll
        for (int i = 0; i < 4; ++i) {
          float v = (accO[g][rb * 4 + i] * fac + myO[d0 + i]) * inv;
          pk |= (uint64_t)f2bf(v) << (16 * i);
        }
        *(uint64_t*)(ob + q * 1536 + h * 128 + d0) = pk;
      }
  }
}

// ---------------------------------------------------------------------------
extern "C" void kernel_launch(void* const* d_in, const int* in_sizes, int n_in,
                              void* d_out, int out_size, void* d_ws,
                              size_t ws_size, hipStream_t stream) {
  const void* txt = d_in[0];
  const void* img = d_in[1];
  const void* rope = d_in[2];
  const void* Wtq = d_in[3];
  const void* Wiq = d_in[4];
  const void* Wto = d_in[5];
  const void* Wio = d_in[6];

  uint16_t* ws = (uint16_t*)d_ws;
  uint16_t* qb = ws;                  // [12][4608][128]
  uint16_t* kb = ws + 7077888L;
  uint16_t* vb = ws + 14155776L;      // [12][4608][128] row-major
  uint16_t* ob = ws + 21233664L;      // [4608][1536]

  const size_t NEED = 108527616ULL;   // 54,263,808 u16 elems
  const int conv = (ws_size >= NEED) ? 1 : 0;

  const void *Atxt = txt, *Aimg = img;
  const void *Bqt = Wtq, *Bqi = Wiq, *Bot = Wto, *Boi = Wio;
  if (conv) {
    convert6<<<dim3(864, 6), 256, 0, stream>>>(txt, img, Wtq, Wiq, Wto, Wio,
                                               ws);
    Atxt = ws + 28311552L;
    Aimg = ws + 29097984L;
    Bqt = ws + 35389440L;
    Bqi = ws + 42467328L;
    Bot = ws + 49545216L;
    Boi = ws + 51904512L;
  }

  qkv_gemm<<<dim3(36, 36), 256, 0, stream>>>(Atxt, Aimg, Bqt, Bqi, rope, txt,
                                             conv, qb, kb, vb);
  attn<<<dim3(72, 12), 256, 0, stream>>>(qb, kb, vb, ob);
  out_gemm<<<dim3(12, 36), 256, 0, stream>>>(ob, Bot, Boi, txt, conv, d_out);
}

// Round 12
// 538.409 us; speedup vs baseline: 1.0736x; 1.0736x over previous
//
#include <hip/hip_runtime.h>
#include <hip/hip_bf16.h>
#include <stdint.h>

// JointAttention: B=1, L=512(txt), N=4096(img), HID=1536, H=12, D=128
// Round 14: attn QBLK=128, no key-split. R11 (2-deep pipeline) was NULL ->
// load latency not binding; residual = per-wave serial chain + per-tile fixed
// costs over too little q-work. Now: 4 waves = 4 q-groups x 32q, each wave
// does the FULL 64-key tile (two interleaved sc chains -> 2x MFMA ILP);
// staged KV serves 128 q (2x amortization); epilogue merge deleted (wave owns
// full key range); LDS 32KB (sK+sVt only); tree max/sum. Fragment algebra
// verbatim from R10/R11 verified core. Grid 36x12=432 (=8x54, XCD swizzle
// bijective). GEMMs unchanged.
// ws (u16 elems): qb[0) kb[7077888) vb[14155776) ob[21233664)
//   txtb[28311552) imgb[29097984) Wqtb[35389440) Wqib[42467328)
//   Wotb[49545216) Woib[51904512) end 54263808 -> 108.5 MB.

typedef __attribute__((ext_vector_type(8))) short short8;
typedef __attribute__((ext_vector_type(4))) float floatx4;
typedef __attribute__((ext_vector_type(16))) float floatx16;

#define DEV __device__ __forceinline__

DEV float bf2f(uint16_t s) {
  union { uint32_t u; float f; } v;
  v.u = (uint32_t)s << 16;
  return v.f;
}
DEV uint16_t f2bf(float f) {
  __hip_bfloat16 h = __float2bfloat16(f);
  return __builtin_bit_cast(uint16_t, h);
}
DEV uint32_t pk2(float a, float b) {
  return (uint32_t)f2bf(a) | ((uint32_t)f2bf(b) << 16);
}

// Distinguish bf16 vs fp32 buffers (majority vote on exponent sanity).
DEV bool detect_bf16(const void* p) {
  const uint16_t* u = (const uint16_t*)p;
  int sane = 0;
  for (int i = 0; i < 64; ++i) {
    int e = (u[2 * i] >> 7) & 0xFF;
    sane += (e > 90 && e < 145) ? 1 : 0;
  }
  return sane >= 40;
}

DEV short8 load8(const void* base, long idx, bool bf) {
  if (bf) return *(const short8*)((const uint16_t*)base + idx);
  const floatx4* f = (const floatx4*)((const float*)base + idx);
  floatx4 a = f[0], b = f[1];
  short8 r;
  r[0] = (short)f2bf(a[0]); r[1] = (short)f2bf(a[1]);
  r[2] = (short)f2bf(a[2]); r[3] = (short)f2bf(a[3]);
  r[4] = (short)f2bf(b[0]); r[5] = (short)f2bf(b[1]);
  r[6] = (short)f2bf(b[2]); r[7] = (short)f2bf(b[3]);
  return r;
}

DEV float loadElem(const void* base, long idx, bool bf) {
  return bf ? bf2f(((const uint16_t*)base)[idx]) : ((const float*)base)[idx];
}

// ---------------------------------------------------------------------------
// One-time fp32->bf16 (or bf16 copy) of the 6 GEMM operand tensors into ws.
__global__ void convert6(const void* s0, const void* s1, const void* s2,
                         const void* s3, const void* s4, const void* s5,
                         uint16_t* ws) {
  const void* s;
  uint16_t* d;
  long n;
  switch (blockIdx.y) {
    case 0: s = s0; d = ws + 28311552L; n = 786432L; break;   // txt
    case 1: s = s1; d = ws + 29097984L; n = 6291456L; break;  // img
    case 2: s = s2; d = ws + 35389440L; n = 7077888L; break;  // W_txt_qkv
    case 3: s = s3; d = ws + 42467328L; n = 7077888L; break;  // W_img_qkv
    case 4: s = s4; d = ws + 49545216L; n = 2359296L; break;  // W_txt_out
    default: s = s5; d = ws + 51904512L; n = 2359296L; break; // W_img_out
  }
  const bool bf = detect_bf16(s);
  const long stride = (long)gridDim.x * blockDim.x * 8;
  for (long i = ((long)blockIdx.x * blockDim.x + threadIdx.x) * 8; i < n;
       i += stride) {
    if (bf) {
      *(short8*)(d + i) = *(const short8*)((const uint16_t*)s + i);
    } else {
      const floatx4* f = (const floatx4*)((const float*)s + i);
      floatx4 a = f[0], b = f[1];
      short8 r;
      r[0] = (short)f2bf(a[0]); r[1] = (short)f2bf(a[1]);
      r[2] = (short)f2bf(a[2]); r[3] = (short)f2bf(a[3]);
      r[4] = (short)f2bf(b[0]); r[5] = (short)f2bf(b[1]);
      r[6] = (short)f2bf(b[2]); r[7] = (short)f2bf(b[3]);
      *(short8*)(d + i) = r;
    }
  }
}

// ---------------------------------------------------------------------------
// acc[4][4] for C tile (bm,bn) of A[M,K] * B[N,K]^T via bf16 MFMA.
// 128x128 tile, BK=32, register staging + ds_write_b128, XOR chunk swizzle.
DEV void gemm_core(const void* A, const void* B, bool abf, bool bbf, long bm,
                   long bn, int K, uint16_t* sA, uint16_t* sB,
                   floatx4 (&acc)[4][4]) {
  const int t = threadIdx.x;
  const int lane = t & 63, wave = t >> 6, l16 = lane & 15, quad = lane >> 4;
  const int srow = t >> 2, c = t & 3, g = c ^ (srow & 3);
  const int wm = (wave >> 1) * 64, wn = (wave & 1) * 64;
  const int fsl = (quad ^ (l16 & 3)) * 8;
  for (int k0 = 0; k0 < K; k0 += 32) {
    short8 a0 = load8(A, (bm + srow) * (long)K + k0 + g * 8, abf);
    short8 a1 = load8(A, (bm + 64 + srow) * (long)K + k0 + g * 8, abf);
    short8 b0 = load8(B, (bn + srow) * (long)K + k0 + g * 8, bbf);
    short8 b1 = load8(B, (bn + 64 + srow) * (long)K + k0 + g * 8, bbf);
    __syncthreads();  // prev-iter frag reads done before overwrite
    *(short8*)(sA + srow * 32 + c * 8) = a0;
    *(short8*)(sA + (64 + srow) * 32 + c * 8) = a1;
    *(short8*)(sB + srow * 32 + c * 8) = b0;
    *(short8*)(sB + (64 + srow) * 32 + c * 8) = b1;
    __syncthreads();
    short8 af[4], bfr[4];
#pragma unroll
    for (int i = 0; i < 4; ++i) {
      af[i] = *(const short8*)(sA + (wm + i * 16 + l16) * 32 + fsl);
      bfr[i] = *(const short8*)(sB + (wn + i * 16 + l16) * 32 + fsl);
    }
#pragma unroll
    for (int i = 0; i < 4; ++i)
#pragma unroll
      for (int j = 0; j < 4; ++j)
        acc[i][j] = __builtin_amdgcn_mfma_f32_16x16x32_bf16(af[i], bfr[j],
                                                            acc[i][j], 0, 0, 0);
  }
}

// ---------------------------------------------------------------------------
// Merged QKV gemm with fused scatter + rope + q-prescale (SCALE*log2e).
// Column tile = one (tensor tt, head h). q/k/v row-major [H][4608][128].
__global__ __launch_bounds__(256, 2) void qkv_gemm(
    const void* Atxt, const void* Aimg, const void* Btxt, const void* Bimg,
    const void* rope, const void* det, int conv, uint16_t* qb, uint16_t* kb,
    uint16_t* vb) {
  __shared__ uint16_t sA[128 * 32], sB[128 * 32];
  const bool dbf = detect_bf16(det);      // original input dtype (rope)
  const bool bf = conv ? true : dbf;      // A/B operand dtype
  const int bmb = blockIdx.y;
  const long g0 = (long)bmb * 128;        // global seq row of this block
  const bool is_img = bmb >= 4;           // 4*128 == 512 txt rows
  const void* A = is_img ? Aimg : Atxt;
  const void* B = is_img ? Bimg : Btxt;
  const long bmA = is_img ? g0 - 512 : g0;
  const long bn = (long)blockIdx.x * 128;
  floatx4 acc[4][4] = {};
  gemm_core(A, B, bf, bf, bmA, bn, 1536, sA, sB, acc);

  const int t = threadIdx.x, lane = t & 63, wave = t >> 6;
  const int l16 = lane & 15, quad = lane >> 4;
  const int wm = (wave >> 1) * 64, wn = (wave & 1) * 64;
  const int th = blockIdx.x;
  const int tt = th / 12, h = th - tt * 12;
  uint16_t* dst = tt == 0 ? qb : (tt == 1 ? kb : vb);
  const bool do_rope = is_img && (tt < 2);
#pragma unroll
  for (int i = 0; i < 4; ++i)
#pragma unroll
    for (int j = 0; j < 4; ++j)
#pragma unroll
      for (int r = 0; r < 4; ++r) {
        long g = g0 + wm + i * 16 + quad * 4 + r;  // global seq row
        int d = wn + j * 16 + l16;
        float v = acc[i][j][r];
        float p = __shfl_xor(v, 1);  // partner element of the rope pair
        if (do_rope) {
          int dp = d & ~1;
          long ri = (g - 512) * 128 + dp;
          float cc = loadElem(rope, ri, dbf);
          float ss = loadElem(rope, ri + 1, dbf);
          v = (d & 1) ? (v * cc + p * ss) : (v * cc - p * ss);
        }
        if (tt == 0) v *= 0.12751745f;  // D^-0.5 * log2(e)
        dst[((long)h * 4608 + g) * 128 + d] = f2bf(v);
      }
}

// ---------------------------------------------------------------------------
// Merged out-projection gemm.
__global__ __launch_bounds__(256, 2) void out_gemm(
    const uint16_t* Abf, const void* Btxt, const void* Bimg, const void* det,
    int conv, void* out) {
  __shared__ uint16_t sA[128 * 32], sB[128 * 32];
  const bool dbf = detect_bf16(det);
  const bool bbf = conv ? true : dbf;
  const int bmb = blockIdx.y;
  const long bm = (long)bmb * 128;
  const void* B = bmb >= 4 ? Bimg : Btxt;
  const long bn = (long)blockIdx.x * 128;
  floatx4 acc[4][4] = {};
  gemm_core(Abf, B, true, bbf, bm, bn, 1536, sA, sB, acc);

  const int t = threadIdx.x, lane = t & 63, wave = t >> 6;
  const int l16 = lane & 15, quad = lane >> 4;
  const int wm = (wave >> 1) * 64, wn = (wave & 1) * 64;
#pragma unroll
  for (int i = 0; i < 4; ++i)
#pragma unroll
    for (int j = 0; j < 4; ++j)
#pragma unroll
      for (int r = 0; r < 4; ++r) {
        long row = bm + wm + i * 16 + quad * 4 + r;
        long col = bn + wn + j * 16 + l16;
        long idx = row * 1536 + col;
        if (dbf) ((uint16_t*)out)[idx] = f2bf(acc[i][j][r]);
        else ((float*)out)[idx] = acc[i][j][r];
      }
}

// ---------------------------------------------------------------------------
// Flash attention, 32x32x16 MFMA swapped operands, QBLK=128 (4 waves x 32 q),
// KVBLK=64, full-key waves (no key-split, no merge). LDS 32KB single-buffer,
// 1-tile register prefetch. Lane l: q = q0 + wave*32 + (l&31), hi = l>>5.
// QK: two independent sc chains (keys 0-31 / 32-63), interleaved MFMAs.
// PV: accO[g] = mfma(V^T, P^T) over 4 key-slices. Swizzles from R10/R11.
__global__ __launch_bounds__(256, 2) void attn(
    const uint16_t* __restrict__ qb, const uint16_t* __restrict__ kb,
    const uint16_t* __restrict__ vb, uint16_t* __restrict__ ob) {
  __shared__ __align__(16) uint16_t sK[64 * 128];   // 16KB chunk-swizzled
  __shared__ __align__(16) uint16_t sVt[128 * 64];  // 16KB [d][64k] packed

  const int t = threadIdx.x;
  const int lane = t & 63, wave = t >> 6;
  const int l31 = lane & 31, hi = lane >> 5;
  // XCD swizzle: bijective since 432 % 8 == 0 (54 blocks per XCD chunk)
  const int bid = blockIdx.y * 36 + blockIdx.x;
  const int sw = (bid & 7) * 54 + (bid >> 3);
  const int h = sw / 36;
  const int q0 = (sw - h * 36) * 128 + wave * 32;

  const uint16_t* Qh = qb + (long)h * 4608 * 128;
  const uint16_t* Kh = kb + (long)h * 4608 * 128;
  const uint16_t* Vh = vb + (long)h * 4608 * 128;

  // Q as B-fragments: aq[dk] = Q[q0+l31][dk*16 + hi*8 .. +8]
  short8 aq[8];
#pragma unroll
  for (int dk = 0; dk < 8; ++dk)
    aq[dk] = *(const short8*)(Qh + (long)(q0 + l31) * 128 + dk * 16 + hi * 8);

  float m_i = -1e30f;
  float accL = 0.f;
  floatx16 accO[4] = {};  // accO[g][r]: d = g*32 + (r&3)+8*(r>>2)+4*hi

  // staging geometry (identical to R10/R11)
  const int krow = t >> 2;        // 0..63
  const int kcb = (t & 3) * 4;    // K chunk base (4 chunks of 8 elems)
  const int vk = (t & 31) * 2;    // V key pair
  const int vdb = (t >> 5) * 16;  // V d base (16 d's per thread)

  short8 kreg[4], vreg[4];

  auto loadKV = [&](int key0) {
    const uint16_t* kp = Kh + (long)(key0 + krow) * 128 + kcb * 8;
    kreg[0] = *(const short8*)(kp);
    kreg[1] = *(const short8*)(kp + 8);
    kreg[2] = *(const short8*)(kp + 16);
    kreg[3] = *(const short8*)(kp + 24);
    const uint16_t* vp = Vh + (long)(key0 + vk) * 128 + vdb;
    vreg[0] = *(const short8*)(vp);
    vreg[1] = *(const short8*)(vp + 8);
    vreg[2] = *(const short8*)(vp + 128);
    vreg[3] = *(const short8*)(vp + 136);
  };
  auto writeKV = [&]() {
#pragma unroll
    for (int j = 0; j < 4; ++j)
      *(short8*)(sK + krow * 128 + (((kcb + j) ^ (krow & 15)) * 8)) = kreg[j];
    char* vd = (char*)sVt;
#pragma unroll
    for (int hf = 0; hf < 2; ++hf)
#pragma unroll
      for (int j = 0; j < 8; ++j) {
        const int d = vdb + hf * 8 + j;
        uint32_t pk = (uint16_t)vreg[hf][j] |
                      ((uint32_t)(uint16_t)vreg[2 + hf][j] << 16);
        *(uint32_t*)(vd + d * 128 + (((vk >> 3) ^ (d & 7)) * 16) +
                     (vk & 7) * 2) = pk;
      }
  };

  loadKV(0);
  writeKV();
  __syncthreads();

  for (int kt = 0; kt < 72; ++kt) {
    if (kt < 71) loadKV((kt + 1) * 64);

    // S^T = K Q^T over full 64 keys: two independent chains, interleaved.
    // sc0[r]: key crow(r,hi), sc1[r]: key 32+crow(r,hi); q = l31.
    floatx16 sc0 = {}, sc1 = {};
    __builtin_amdgcn_s_setprio(1);
#pragma unroll
    for (int dk = 0; dk < 8; ++dk) {
      const int ch = ((dk * 2 + hi) ^ (l31 & 15)) * 8;
      short8 ak0 = *(const short8*)(sK + l31 * 128 + ch);
      short8 ak1 = *(const short8*)(sK + (32 + l31) * 128 + ch);
      sc0 = __builtin_amdgcn_mfma_f32_32x32x16_bf16(ak0, aq[dk], sc0, 0, 0, 0);
      sc1 = __builtin_amdgcn_mfma_f32_32x32x16_bf16(ak1, aq[dk], sc1, 0, 0, 0);
    }
    __builtin_amdgcn_s_setprio(0);

    // in-register online softmax over 32 regs (full 64-key slice via partner)
    float m0 = fmaxf(fmaxf(fmaxf(sc0[0], sc0[1]), fmaxf(sc0[2], sc0[3])),
                     fmaxf(fmaxf(sc0[4], sc0[5]), fmaxf(sc0[6], sc0[7])));
    float m1 = fmaxf(fmaxf(fmaxf(sc0[8], sc0[9]), fmaxf(sc0[10], sc0[11])),
                     fmaxf(fmaxf(sc0[12], sc0[13]), fmaxf(sc0[14], sc0[15])));
    float m2 = fmaxf(fmaxf(fmaxf(sc1[0], sc1[1]), fmaxf(sc1[2], sc1[3])),
                     fmaxf(fmaxf(sc1[4], sc1[5]), fmaxf(sc1[6], sc1[7])));
    float m3 = fmaxf(fmaxf(fmaxf(sc1[8], sc1[9]), fmaxf(sc1[10], sc1[11])),
                     fmaxf(fmaxf(sc1[12], sc1[13]), fmaxf(sc1[14], sc1[15])));
    float mx = fmaxf(fmaxf(m0, m1), fmaxf(m2, m3));
    mx = fmaxf(mx, __shfl_xor(mx, 32));
    if (!__all(mx - m_i <= 11.5f)) {
      float mn = fmaxf(m_i, mx);
      float al = exp2f(m_i - mn);
      m_i = mn;
      accL *= al;
#pragma unroll
      for (int g = 0; g < 4; ++g)
#pragma unroll
        for (int r = 0; r < 16; ++r) accO[g][r] *= al;
    }
#pragma unroll
    for (int r = 0; r < 16; ++r) sc0[r] = exp2f(sc0[r] - m_i);
#pragma unroll
    for (int r = 0; r < 16; ++r) sc1[r] = exp2f(sc1[r] - m_i);
    // tree sum of 32 regs
    float s0 = 0.f, s1 = 0.f;
#pragma unroll
    for (int r = 0; r < 8; ++r) s0 += sc0[r] + sc0[8 + r];
#pragma unroll
    for (int r = 0; r < 8; ++r) s1 += sc1[r] + sc1[8 + r];
    float s = s0 + s1;
    accL += s + __shfl_xor(s, 32);

    // build P^T B-fragments pb[ks] (keys ks*16 + hi*8 + 0..7), ks=0..3
    short8 pb[4];
#pragma unroll
    for (int tk = 0; tk < 2; ++tk) {
      const floatx16& sc = tk ? sc1 : sc0;
#pragma unroll
      for (int sp = 0; sp < 2; ++sp) {
        uint32_t cA = pk2(sc[sp * 8 + 0], sc[sp * 8 + 1]);
        uint32_t cB = pk2(sc[sp * 8 + 2], sc[sp * 8 + 3]);
        uint32_t cC = pk2(sc[sp * 8 + 4], sc[sp * 8 + 5]);
        uint32_t cD = pk2(sc[sp * 8 + 6], sc[sp * 8 + 7]);
        uint32_t xA = (uint32_t)__shfl_xor((int)cA, 32);
        uint32_t xB = (uint32_t)__shfl_xor((int)cB, 32);
        uint32_t xC = (uint32_t)__shfl_xor((int)cC, 32);
        uint32_t xD = (uint32_t)__shfl_xor((int)cD, 32);
        union { short8 v; uint32_t u[4]; } w;
        w.u[0] = hi ? xC : cA;
        w.u[1] = hi ? xD : cB;
        w.u[2] = hi ? cC : xA;
        w.u[3] = hi ? cD : xB;
        pb[tk * 2 + sp] = w.v;
      }
    }

    // O^T += V^T P^T : accO[g] over d-group g, 4 key-slices each
    __builtin_amdgcn_s_setprio(1);
#pragma unroll
    for (int g = 0; g < 4; ++g) {
      const int d = g * 32 + l31;
#pragma unroll
      for (int ks = 0; ks < 4; ++ks) {
        short8 av = *(const short8*)(
            (const char*)sVt + d * 128 + (((ks * 2 + hi) ^ (d & 7)) * 16));
        accO[g] =
            __builtin_amdgcn_mfma_f32_32x32x16_bf16(av, pb[ks], accO[g], 0, 0, 0);
      }
    }
    __builtin_amdgcn_s_setprio(0);

    __syncthreads();  // all waves done reading sK/sVt
    if (kt < 71) {
      writeKV();      // stage tile kt+1 (vmcnt waits here)
      __syncthreads();
    }
  }

  // ---- epilogue: direct normalize + store (no merge needed) ----
  const float inv = 1.f / accL;
  const long q = q0 + l31;
#pragma unroll
  for (int g = 0; g < 4; ++g)
#pragma unroll
    for (int rb = 0; rb < 4; ++rb) {
      const int d0 = g * 32 + 8 * rb + 4 * hi;
      uint64_t pk = 0;
#pragma unroll
      for (int i = 0; i < 4; ++i) {
        float v = accO[g][rb * 4 + i] * inv;
        pk |= (uint64_t)f2bf(v) << (16 * i);
      }
      *(uint64_t*)(ob + q * 1536 + h * 128 + d0) = pk;
    }
}

// ---------------------------------------------------------------------------
extern "C" void kernel_launch(void* const* d_in, const int* in_sizes, int n_in,
                              void* d_out, int out_size, void* d_ws,
                              size_t ws_size, hipStream_t stream) {
  const void* txt = d_in[0];
  const void* img = d_in[1];
  const void* rope = d_in[2];
  const void* Wtq = d_in[3];
  const void* Wiq = d_in[4];
  const void* Wto = d_in[5];
  const void* Wio = d_in[6];

  uint16_t* ws = (uint16_t*)d_ws;
  uint16_t* qb = ws;                  // [12][4608][128]
  uint16_t* kb = ws + 7077888L;
  uint16_t* vb = ws + 14155776L;      // [12][4608][128] row-major
  uint16_t* ob = ws + 21233664L;      // [4608][1536]

  const size_t NEED = 108527616ULL;   // 54,263,808 u16 elems
  const int conv = (ws_size >= NEED) ? 1 : 0;

  const void *Atxt = txt, *Aimg = img;
  const void *Bqt = Wtq, *Bqi = Wiq, *Bot = Wto, *Boi = Wio;
  if (conv) {
    convert6<<<dim3(864, 6), 256, 0, stream>>>(txt, img, Wtq, Wiq, Wto, Wio,
                                               ws);
    Atxt = ws + 28311552L;
    Aimg = ws + 29097984L;
    Bqt = ws + 35389440L;
    Bqi = ws + 42467328L;
    Bot = ws + 49545216L;
    Boi = ws + 51904512L;
  }

  qkv_gemm<<<dim3(36, 36), 256, 0, stream>>>(Atxt, Aimg, Bqt, Bqi, rope, txt,
                                             conv, qb, kb, vb);
  attn<<<dim3(36, 12), 256, 0, stream>>>(qb, kb, vb, ob);
  out_gemm<<<dim3(12, 36), 256, 0, stream>>>(ob, Bot, Boi, txt, conv, d_out);
}